// Round 16
// baseline (893.181 us; speedup 1.0000x reference)
//
#include <hip/hip_runtime.h>
#include <hip/hip_fp8.h>

// Problem constants
#define N_TOK 4096   // H*W
#define C_DIM 256
#define D_DIM 32

typedef float f32x4 __attribute__((ext_vector_type(4)));
typedef short short8 __attribute__((ext_vector_type(8)));
typedef unsigned short u16;
typedef unsigned char u8;
typedef long long i64;

__device__ __forceinline__ u16 f2bf(float f) {
    unsigned int u = __builtin_bit_cast(unsigned int, f);
    u += 0x7fffu + ((u >> 16) & 1u);   // round-to-nearest-even
    return (u16)(u >> 16);
}
__device__ __forceinline__ float bf2f(u16 h) {
    unsigned int u = ((unsigned int)h) << 16;
    return __builtin_bit_cast(float, u);
}
__device__ __forceinline__ float exp2_fast(float x) {  // 2^x, compiler-managed
#if __has_builtin(__builtin_amdgcn_exp2f)
    return __builtin_amdgcn_exp2f(x);
#else
    return exp2f(x);
#endif
}
// pack 2 f32 -> 2 OCP e4m3 bytes into half of a dword (HI is compile-time)
template<bool HI>
__device__ __forceinline__ int pk_fp8(float a, float b, int old) {
#if __has_builtin(__builtin_amdgcn_cvt_pk_fp8_f32)
    return __builtin_amdgcn_cvt_pk_fp8_f32(a, b, old, HI);
#else
    __hip_fp8_e4m3 fa(a), fb(b);
    int v = (int)fa.__x | ((int)fb.__x << 8);
    return HI ? ((old & 0xffff) | (v << 16)) : ((old & ~0xffff) | (v & 0xffff));
#endif
}
__device__ __forceinline__ u8 f2fp8(float f) {
    return (u8)(pk_fp8<false>(f, f, 0) & 0xff);
}

// Packed V layout (fp8 e4m3 bytes), per slice (1 MB):
//   byte = jblk*8192 + p*2048 + c*8 + (j&7),  jblk = j>>5,  p = (j>>3)&3
// (jblk, p, c-half) chunk = contiguous 1 KB -> linear stage copy.

// ---------------------------------------------------------------------------
// Kernel 1: q/k projection.  q = (wq*x1 + bq)*log2e, k = wk*x2 + bk
// Output layout: Q[slice][i][d], K[slice][j][d]  (d contiguous, bf16)
// ---------------------------------------------------------------------------
__global__ __launch_bounds__(256) void qk_proj(
    const float* __restrict__ x1, const float* __restrict__ x2,
    const float* __restrict__ wq1, const float* __restrict__ bq1,
    const float* __restrict__ wk1, const float* __restrict__ bk1,
    const float* __restrict__ wq2, const float* __restrict__ bq2,
    const float* __restrict__ wk2, const float* __restrict__ bk2,
    u16* __restrict__ wsQ, u16* __restrict__ wsK)
{
    __shared__ float w_lds[32 * 256];
    const int ib = blockIdx.x;
    const int comb = blockIdx.y;
    const int b = comb & 3;
    const int branch = (comb >> 2) & 1;
    const int qk = comb >> 3;

    const float* x = qk ? x2 : x1;           // q from x1; k from x2
    const float* w; const float* bias; u16* dst;
    if (qk == 0) { w = branch ? wq2 : wq1; bias = branch ? bq2 : bq1; dst = wsQ; }
    else         { w = branch ? wk2 : wk1; bias = branch ? bk2 : bk1; dst = wsK; }
    const int slice = branch * 4 + b;
    dst += (size_t)slice * N_TOK * D_DIM;
    const float osc = (qk == 0) ? 1.44269504088896341f : 1.0f;

    const int tid = threadIdx.x;
    for (int t = tid; t < 32 * 256; t += 256) w_lds[t] = w[t];
    __syncthreads();

    const int il = tid & 63;
    const int db = tid >> 6;                 // 0..3 -> d = db*8 + mm
    const float* xc = x + (size_t)b * C_DIM * N_TOK + ib * 64 + il;

    float acc[8] = {0.f,0.f,0.f,0.f,0.f,0.f,0.f,0.f};
    for (int c4 = 0; c4 < 256; c4 += 4) {
        const float xv0 = xc[(size_t)(c4 + 0) * N_TOK];
        const float xv1 = xc[(size_t)(c4 + 1) * N_TOK];
        const float xv2 = xc[(size_t)(c4 + 2) * N_TOK];
        const float xv3 = xc[(size_t)(c4 + 3) * N_TOK];
#pragma unroll
        for (int mm = 0; mm < 8; ++mm) {
            const float4 wv = *(const float4*)&w_lds[(db * 8 + mm) * 256 + c4];
            acc[mm] += xv0 * wv.x + xv1 * wv.y + xv2 * wv.z + xv3 * wv.w;
        }
    }
    short8 pack;
#pragma unroll
    for (int mm = 0; mm < 8; ++mm)
        pack[mm] = (short)f2bf((acc[mm] + bias[db * 8 + mm]) * osc);
    *(short8*)(dst + (size_t)(ib * 64 + il) * D_DIM + db * 8) = pack;
}

// ---------------------------------------------------------------------------
// Kernel 2: v projection via MFMA, writing PACKED fp8 V.
// block 256 (4 waves, 2x2 wave grid), tile 128c x 128j, K=256 in 8 steps.
// grid (32 jt, 2 ct, 8 slices)
// ---------------------------------------------------------------------------
__device__ __forceinline__ void stage_xt(u16* xtb, const float* xb, int ks,
                                         int wave, int lane)
{
    // XT[j][k] (32 k per buf, 64B rows), chunk kc stored at pos kc ^ ((j>>1)&3)
    const int j  = (wave & 1) * 64 + lane;
    const int cb = (wave >> 1) * 16;       // k (cin) base, 16 per thread
    const float* xp = xb + (size_t)(ks * 32 + cb) * N_TOK + j;
    u16 vals[16];
#pragma unroll
    for (int qq = 0; qq < 16; ++qq) vals[qq] = f2bf(xp[(size_t)qq * N_TOK]);
    const int swz = (j >> 1) & 3;
    u16* row = xtb + j * 32;
    const int c0 = cb >> 3;
    *(short8*)&row[((c0    ) ^ swz) * 8] = *(const short8*)&vals[0];
    *(short8*)&row[((c0 + 1) ^ swz) * 8] = *(const short8*)&vals[8];
}

__global__ __launch_bounds__(256, 2) void v_proj(
    const float* __restrict__ x2,
    const float* __restrict__ wv1, const float* __restrict__ bv1,
    const float* __restrict__ wv2, const float* __restrict__ bv2,
    u8* __restrict__ wsV)
{
    __shared__ __align__(16) u16 wl[128 * 256];     // [c][k] swizzled, 64 KB
    __shared__ __align__(16) u16 xt[2][128 * 32];   // [j][k] swizzled, 16 KB

    const int jt = blockIdx.x, ct = blockIdx.y, s = blockIdx.z;
    const int branch = s >> 2, b = s & 3;
    const float* w    = branch ? wv2 : wv1;
    const float* bias = branch ? bv2 : bv1;
    u8* dstB = wsV + (size_t)s * N_TOK * C_DIM;     // packed fp8 slice (1 MB)
    const float* xb = x2 + (size_t)b * C_DIM * N_TOK + jt * 128;

    const int tid = threadIdx.x;
    const int wave = tid >> 6, lane = tid & 63;
    const int wr = wave >> 1, wc = wave & 1;
    const int g = lane >> 4, li = lane & 15;

    // ---- stage W[128c][256k] -> bf16 LDS, chunk kc at pos kc ^ (c&7)
    {
        const int c = tid >> 1;
        const int kh = (tid & 1) * 128;
        const float* wrow = w + (size_t)(ct * 128 + c) * C_DIM + kh;
        u16* lrow = wl + c * 256;
#pragma unroll
        for (int kk = 0; kk < 128; kk += 8) {
            const float4 a0 = *(const float4*)&wrow[kk];
            const float4 a1 = *(const float4*)&wrow[kk + 4];
            u16 tmp[8] = {f2bf(a0.x), f2bf(a0.y), f2bf(a0.z), f2bf(a0.w),
                          f2bf(a1.x), f2bf(a1.y), f2bf(a1.z), f2bf(a1.w)};
            const int kc = (kh + kk) >> 3;
            *(short8*)&lrow[(kc ^ (c & 7)) * 8] = *(const short8*)tmp;
        }
    }
    stage_xt(&xt[0][0], xb, 0, wave, lane);
    __syncthreads();

    f32x4 acc[4][4];
#pragma unroll
    for (int mf = 0; mf < 4; ++mf)
#pragma unroll
        for (int nf = 0; nf < 4; ++nf) acc[mf][nf] = (f32x4){0.f, 0.f, 0.f, 0.f};

    int buf = 0;
    for (int ks = 0; ks < 8; ++ks) {
        if (ks < 7) stage_xt(&xt[buf ^ 1][0], xb, ks + 1, wave, lane);

        short8 af[4], bf[4];
#pragma unroll
        for (int mf = 0; mf < 4; ++mf) {
            const int c = wr * 64 + mf * 16 + li;
            af[mf] = *(const short8*)&wl[c * 256 + (((ks * 4 + g) ^ (li & 7)) * 8)];
        }
#pragma unroll
        for (int nf = 0; nf < 4; ++nf) {
            const int j = wc * 64 + nf * 16 + li;
            bf[nf] = *(const short8*)&xt[buf][j * 32 + ((g ^ ((j >> 1) & 3)) * 8)];
        }
        __builtin_amdgcn_s_setprio(1);
#pragma unroll
        for (int mf = 0; mf < 4; ++mf)
#pragma unroll
            for (int nf = 0; nf < 4; ++nf)
                acc[mf][nf] = __builtin_amdgcn_mfma_f32_16x16x32_bf16(
                    af[mf], bf[nf], acc[mf][nf], 0, 0, 0);
        __builtin_amdgcn_s_setprio(0);
        __syncthreads();
        buf ^= 1;
    }

    // ---- epilogue: write packed fp8 V
#pragma unroll
    for (int mf = 0; mf < 4; ++mf) {
#pragma unroll
        for (int r = 0; r < 4; ++r) {
            const int c = ct * 128 + wr * 64 + mf * 16 + 4 * g + r;
            const float bv = bias[c];
#pragma unroll
            for (int nf = 0; nf < 4; ++nf) {
                const int j = jt * 128 + wc * 64 + nf * 16 + li;
                dstB[(size_t)(j >> 5) * 8192 + ((j >> 3) & 3) * 2048
                     + c * 8 + (j & 7)] = f2fp8(acc[mf][nf][r] + bv);
            }
        }
    }
}

// ---------------------------------------------------------------------------
// Kernel 3: flash attention, static-max exp2 softmax, c-split, fp8 PV,
// 4-way j-split for FULL occupancy.
// block 512 = 8 waves = 4 grp (j-quarters, 32 periods each) x 2 wg (i-halves);
// R=2 (32 i/wave), acc[2][8] = 64 VGPRs; __launch_bounds__(512,8) -> VGPR<=64,
// LDS 36.9KB -> 4 blocks/CU x 8 waves = 32 waves/CU = 8/SIMD (100% occupancy,
// vs round-12's grid-capped 4/SIMD).  Same per-j traffic as round 12.
// Merge: 2-round tree (grp1->0, grp3->2, then 2->0) via vlds scratch.
// grid 1024: n = slice + 8*(ib + 64*ct); slice = n%8 -> XCD affinity.
// ---------------------------------------------------------------------------
__global__ __launch_bounds__(512, 8) void attn_fwd(
    const u16* __restrict__ Q, const u16* __restrict__ K,
    const u8* __restrict__ V, u16* __restrict__ O)
{
    __shared__ __align__(16) u8 vlds[4][2][4096];   // [grp][buf] 32 KB
    __shared__ float lscr[4][2][64][2];             // [grp][wg][lane][it] 4 KB

    const int n  = blockIdx.x;
    const int s  = n & 7;              // slice -> XCD (n%8)
    const int ib = (n >> 3) & 63;      // i-block of 64 rows
    const int ct = n >> 9;             // c-half
    const u16* q = Q + (size_t)s * N_TOK * D_DIM;
    const u16* k = K + (size_t)s * N_TOK * D_DIM;
    const u8*  v = V + (size_t)s * N_TOK * C_DIM + ct * 1024;  // c-half in p-chunks
    u16*       o = O + (size_t)s * N_TOK * C_DIM + ct * 128;

    const int tid  = threadIdx.x;
    const int wave = tid >> 6;
    const int lane = tid & 63;
    const int grp  = wave >> 1;        // j-quarter (0..3)
    const int wg   = wave & 1;         // i-half
    const int g    = lane >> 4;
    const int li   = lane & 15;
    const int i0   = ib * 64 + wg * 32;
    const int jbase = grp * (N_TOK / 4);
    const int NP = N_TOK / 4 / 32;     // 32 periods of 32 j

    short8 qf[2];
    qf[0] = *(const short8*)(q + (size_t)(i0 + li) * D_DIM + 8 * g);
    qf[1] = *(const short8*)(q + (size_t)(i0 + 16 + li) * D_DIM + 8 * g);

    f32x4 acc[2][8];
#pragma unroll
    for (int it = 0; it < 2; ++it)
#pragma unroll
        for (int cf = 0; cf < 8; ++cf) acc[it][cf] = (f32x4){0.f, 0.f, 0.f, 0.f};
    float lsum[2] = {0.f, 0.f};

    // prologue: V tile 0 (2 x 1KB linear chunks per wave) + K(0)
    {
        const u8* tile = v + (size_t)(jbase >> 5) * 8192;
#pragma unroll
        for (int ii = 0; ii < 2; ++ii) {
            const int pc = wg * 2 + ii;
            __builtin_amdgcn_global_load_lds(
                (const __attribute__((address_space(1))) void*)(tile + pc * 2048 + lane * 16),
                (__attribute__((address_space(3))) void*)(&vlds[grp][0][0] + pc * 1024),
                16, 0, 0);
        }
    }
    __syncthreads();

    int buf = 0;
    for (int p = 0; p < NP; ++p) {
        if (p < NP - 1) {               // stage next V tile (async)
            const u8* tile = v + (size_t)((jbase + (p + 1) * 32) >> 5) * 8192;
            u8* dst = &vlds[grp][buf ^ 1][0];
#pragma unroll
            for (int ii = 0; ii < 2; ++ii) {
                const int pc = wg * 2 + ii;
                __builtin_amdgcn_global_load_lds(
                    (const __attribute__((address_space(1))) void*)(tile + pc * 2048 + lane * 16),
                    (__attribute__((address_space(3))) void*)(dst + pc * 1024),
                    16, 0, 0);
            }
        }

        // K fragments for this period (L2-resident; TLP hides latency)
        const int j0 = jbase + p * 32;
        const short8 ke = *(const short8*)(k + (size_t)(j0 + 2 * li    ) * D_DIM + 8 * g);
        const short8 ko = *(const short8*)(k + (size_t)(j0 + 2 * li + 1) * D_DIM + 8 * g);

        const f32x4 z = (f32x4){0.f, 0.f, 0.f, 0.f};
        i64 paL[2];
#pragma unroll
        for (int it = 0; it < 2; ++it) {
            f32x4 se = __builtin_amdgcn_mfma_f32_16x16x32_bf16(ke, qf[it], z, 0, 0, 0);
            f32x4 so = __builtin_amdgcn_mfma_f32_16x16x32_bf16(ko, qf[it], z, 0, 0, 0);
            float pe[4], po[4];
#pragma unroll
            for (int r = 0; r < 4; ++r) {
                pe[r] = exp2_fast(se[r]);   // P = 2^(s*log2e), static shift
                po[r] = exp2_fast(so[r]);
            }
            lsum[it] += ((pe[0] + po[0]) + (pe[1] + po[1]))
                      + ((pe[2] + po[2]) + (pe[3] + po[3]));
            // pack P -> 8 fp8 bytes: byte e = j (8g+e); e=2r even (pe), 2r+1 odd (po)
            int w0 = pk_fp8<false>(pe[0], po[0], 0);
            w0     = pk_fp8<true >(pe[1], po[1], w0);
            int w1 = pk_fp8<false>(pe[2], po[2], 0);
            w1     = pk_fp8<true >(pe[3], po[3], w1);
            paL[it] = (i64)(((unsigned long long)(unsigned)w1 << 32) | (unsigned)w0);
        }

        // O += P * V^T ; fp8 MFMA, one b64 V read feeds both i-tiles
        const u8* vb = &vlds[grp][buf][0];
        const i64* vbL = (const i64*)(vb + g * 1024 + li * 8);
        __builtin_amdgcn_s_setprio(1);
#pragma unroll
        for (int cf = 0; cf < 8; ++cf) {
            const i64 vfL = vbL[cf * 16];
            acc[0][cf] = __builtin_amdgcn_mfma_f32_16x16x32_fp8_fp8(paL[0], vfL, acc[0][cf], 0, 0, 0);
            acc[1][cf] = __builtin_amdgcn_mfma_f32_16x16x32_fp8_fp8(paL[1], vfL, acc[1][cf], 0, 0, 0);
        }
        __builtin_amdgcn_s_setprio(0);
        __syncthreads();
        buf ^= 1;
    }

    // ---- lsum publish (lane-reduced) ----
#pragma unroll
    for (int it = 0; it < 2; ++it) {
        lsum[it] += __shfl_xor(lsum[it], 16);
        lsum[it] += __shfl_xor(lsum[it], 32);
        lscr[grp][wg][lane][it] = lsum[it];
    }

    // ---- merge 4 j-quarter partials: 2-round tree, pure add ----
    f32x4* pv = (f32x4*)&vlds[0][0][0];   // 32 KB scratch (2048 f32x4)
#pragma unroll
    for (int it = 0; it < 2; ++it) {
        // round 1: grp1 -> grp0, grp3 -> grp2
        __syncthreads();
        if (grp & 1) {
#pragma unroll
            for (int cf = 0; cf < 8; ++cf)
                pv[(((grp >> 1) * 2 + wg) * 8 + cf) * 64 + lane] = acc[it][cf];
        }
        __syncthreads();
        if (!(grp & 1)) {
#pragma unroll
            for (int cf = 0; cf < 8; ++cf) {
                const f32x4 o4 = pv[(((grp >> 1) * 2 + wg) * 8 + cf) * 64 + lane];
                acc[it][cf][0] += o4[0]; acc[it][cf][1] += o4[1];
                acc[it][cf][2] += o4[2]; acc[it][cf][3] += o4[3];
            }
        }
        // round 2: grp2 -> grp0
        __syncthreads();
        if (grp == 2) {
#pragma unroll
            for (int cf = 0; cf < 8; ++cf)
                pv[(wg * 8 + cf) * 64 + lane] = acc[it][cf];
        }
        __syncthreads();
        if (grp == 0) {
#pragma unroll
            for (int cf = 0; cf < 8; ++cf) {
                const f32x4 o4 = pv[(wg * 8 + cf) * 64 + lane];
                acc[it][cf][0] += o4[0]; acc[it][cf][1] += o4[1];
                acc[it][cf][2] += o4[2]; acc[it][cf][3] += o4[3];
            }
        }
    }

    if (grp == 0) {
#pragma unroll
        for (int it = 0; it < 2; ++it) {
            const float linv = 1.0f /
                (lscr[0][wg][lane][it] + lscr[1][wg][lane][it] +
                 lscr[2][wg][lane][it] + lscr[3][wg][lane][it]);
            float lr[4];
#pragma unroll
            for (int r = 0; r < 4; ++r) lr[r] = __shfl(linv, 4 * g + r);
#pragma unroll
            for (int cf = 0; cf < 8; ++cf)
#pragma unroll
                for (int r = 0; r < 4; ++r)
                    o[(size_t)(i0 + it * 16 + 4 * g + r) * C_DIM + cf * 16 + li] =
                        f2bf(acc[it][cf][r] * lr[r]);
        }
    }
}

// ---------------------------------------------------------------------------
// Kernel 4: out[b][c][i] = x1 + x2 + O1[b][i][c] + O2[b][i][c]  (LDS transpose)
// ---------------------------------------------------------------------------
__global__ __launch_bounds__(256) void epilogue(
    const float* __restrict__ x1, const float* __restrict__ x2,
    const u16* __restrict__ O, float* __restrict__ out)
{
    __shared__ float tl[64][65];
    const int it = blockIdx.x, ct = blockIdx.y, b = blockIdx.z;
    const int tid = threadIdx.x;
    const int cl = tid & 63, r0 = tid >> 6;

    const u16* O1 = O + (size_t)(b)     * N_TOK * C_DIM;
    const u16* O2 = O + (size_t)(4 + b) * N_TOK * C_DIM;

#pragma unroll
    for (int rr = 0; rr < 16; ++rr) {
        const int il = r0 + rr * 4;
        const size_t off = (size_t)(it * 64 + il) * C_DIM + ct * 64 + cl;
        tl[il][cl] = bf2f(O1[off]) + bf2f(O2[off]);
    }
    __syncthreads();
#pragma unroll
    for (int rr = 0; rr < 16; ++rr) {
        const int c2 = r0 + rr * 4;
        const size_t idx = ((size_t)b * C_DIM + ct * 64 + c2) * N_TOK + it * 64 + cl;
        out[idx] = x1[idx] + x2[idx] + tl[cl][c2];
    }
}

// ---------------------------------------------------------------------------
extern "C" void kernel_launch(void* const* d_in, const int* in_sizes, int n_in,
                              void* d_out, int out_size, void* d_ws, size_t ws_size,
                              hipStream_t stream)
{
    const float* x1  = (const float*)d_in[0];
    const float* x2  = (const float*)d_in[1];
    const float* wq1 = (const float*)d_in[2];
    const float* bq1 = (const float*)d_in[3];
    const float* wk1 = (const float*)d_in[4];
    const float* bk1 = (const float*)d_in[5];
    const float* wv1 = (const float*)d_in[6];
    const float* bv1 = (const float*)d_in[7];
    const float* wq2 = (const float*)d_in[8];
    const float* bq2 = (const float*)d_in[9];
    const float* wk2 = (const float*)d_in[10];
    const float* bk2 = (const float*)d_in[11];
    const float* wv2 = (const float*)d_in[12];
    const float* bv2 = (const float*)d_in[13];
    float* out = (float*)d_out;

    // ws layout: Q bf16 2MB | K bf16 2MB | V fp8 packed 8MB | O bf16 16MB
    u16* wsQ = (u16*)d_ws;
    u16* wsK = wsQ + (size_t)8 * N_TOK * D_DIM;
    u8*  wsV = (u8*)(wsK + (size_t)8 * N_TOK * D_DIM);
    u16* wsO = (u16*)(wsV + (size_t)8 * N_TOK * C_DIM);

    qk_proj<<<dim3(64, 16), 256, 0, stream>>>(x1, x2, wq1, bq1, wk1, bk1,
                                              wq2, bq2, wk2, bk2, wsQ, wsK);
    v_proj<<<dim3(32, 2, 8), 256, 0, stream>>>(x2, wv1, bv1, wv2, bv2, wsV);
    attn_fwd<<<dim3(1024), 512, 0, stream>>>(wsQ, wsK, wsV, wsO);
    epilogue<<<dim3(64, 4, 4), 256, 0, stream>>>(x1, x2, wsO, out);
}

// Round 17
// 150.367 us; speedup vs baseline: 5.9400x; 5.9400x over previous
//
#include <hip/hip_runtime.h>
#include <hip/hip_fp8.h>

// Problem constants
#define N_TOK 4096   // H*W
#define C_DIM 256
#define D_DIM 32

typedef float f32x4 __attribute__((ext_vector_type(4)));
typedef short short8 __attribute__((ext_vector_type(8)));
typedef unsigned short u16;
typedef unsigned char u8;
typedef long long i64;

__device__ __forceinline__ u16 f2bf(float f) {
    unsigned int u = __builtin_bit_cast(unsigned int, f);
    u += 0x7fffu + ((u >> 16) & 1u);   // round-to-nearest-even
    return (u16)(u >> 16);
}
__device__ __forceinline__ float bf2f(u16 h) {
    unsigned int u = ((unsigned int)h) << 16;
    return __builtin_bit_cast(float, u);
}
__device__ __forceinline__ float exp2_fast(float x) {  // 2^x, compiler-managed
#if __has_builtin(__builtin_amdgcn_exp2f)
    return __builtin_amdgcn_exp2f(x);
#else
    return exp2f(x);
#endif
}
// pack 2 f32 -> 2 OCP e4m3 bytes into half of a dword (HI is compile-time)
template<bool HI>
__device__ __forceinline__ int pk_fp8(float a, float b, int old) {
#if __has_builtin(__builtin_amdgcn_cvt_pk_fp8_f32)
    return __builtin_amdgcn_cvt_pk_fp8_f32(a, b, old, HI);
#else
    __hip_fp8_e4m3 fa(a), fb(b);
    int v = (int)fa.__x | ((int)fb.__x << 8);
    return HI ? ((old & 0xffff) | (v << 16)) : ((old & ~0xffff) | (v & 0xffff));
#endif
}
__device__ __forceinline__ u8 f2fp8(float f) {
    return (u8)(pk_fp8<false>(f, f, 0) & 0xff);
}

// Packed V layout (fp8 e4m3 bytes), per slice (1 MB):
//   byte = jblk*8192 + p*2048 + c*8 + (j&7),  jblk = j>>5,  p = (j>>3)&3
// (jblk, p, c-half) chunk = contiguous 1 KB -> linear stage copy.

// ---------------------------------------------------------------------------
// Kernel 1: q/k projection.  q = (wq*x1 + bq)*log2e, k = wk*x2 + bk
// Output layout: Q[slice][i][d], K[slice][j][d]  (d contiguous, bf16)
// ---------------------------------------------------------------------------
__global__ __launch_bounds__(256) void qk_proj(
    const float* __restrict__ x1, const float* __restrict__ x2,
    const float* __restrict__ wq1, const float* __restrict__ bq1,
    const float* __restrict__ wk1, const float* __restrict__ bk1,
    const float* __restrict__ wq2, const float* __restrict__ bq2,
    const float* __restrict__ wk2, const float* __restrict__ bk2,
    u16* __restrict__ wsQ, u16* __restrict__ wsK)
{
    __shared__ float w_lds[32 * 256];
    const int ib = blockIdx.x;
    const int comb = blockIdx.y;
    const int b = comb & 3;
    const int branch = (comb >> 2) & 1;
    const int qk = comb >> 3;

    const float* x = qk ? x2 : x1;           // q from x1; k from x2
    const float* w; const float* bias; u16* dst;
    if (qk == 0) { w = branch ? wq2 : wq1; bias = branch ? bq2 : bq1; dst = wsQ; }
    else         { w = branch ? wk2 : wk1; bias = branch ? bk2 : bk1; dst = wsK; }
    const int slice = branch * 4 + b;
    dst += (size_t)slice * N_TOK * D_DIM;
    const float osc = (qk == 0) ? 1.44269504088896341f : 1.0f;

    const int tid = threadIdx.x;
    for (int t = tid; t < 32 * 256; t += 256) w_lds[t] = w[t];
    __syncthreads();

    const int il = tid & 63;
    const int db = tid >> 6;                 // 0..3 -> d = db*8 + mm
    const float* xc = x + (size_t)b * C_DIM * N_TOK + ib * 64 + il;

    float acc[8] = {0.f,0.f,0.f,0.f,0.f,0.f,0.f,0.f};
    for (int c4 = 0; c4 < 256; c4 += 4) {
        const float xv0 = xc[(size_t)(c4 + 0) * N_TOK];
        const float xv1 = xc[(size_t)(c4 + 1) * N_TOK];
        const float xv2 = xc[(size_t)(c4 + 2) * N_TOK];
        const float xv3 = xc[(size_t)(c4 + 3) * N_TOK];
#pragma unroll
        for (int mm = 0; mm < 8; ++mm) {
            const float4 wv = *(const float4*)&w_lds[(db * 8 + mm) * 256 + c4];
            acc[mm] += xv0 * wv.x + xv1 * wv.y + xv2 * wv.z + xv3 * wv.w;
        }
    }
    short8 pack;
#pragma unroll
    for (int mm = 0; mm < 8; ++mm)
        pack[mm] = (short)f2bf((acc[mm] + bias[db * 8 + mm]) * osc);
    *(short8*)(dst + (size_t)(ib * 64 + il) * D_DIM + db * 8) = pack;
}

// ---------------------------------------------------------------------------
// Kernel 2: v projection via MFMA, writing PACKED fp8 V.
// block 256 (4 waves, 2x2 wave grid), tile 128c x 128j, K=256 in 8 steps.
// grid (32 jt, 2 ct, 8 slices)
// ---------------------------------------------------------------------------
__device__ __forceinline__ void stage_xt(u16* xtb, const float* xb, int ks,
                                         int wave, int lane)
{
    // XT[j][k] (32 k per buf, 64B rows), chunk kc stored at pos kc ^ ((j>>1)&3)
    const int j  = (wave & 1) * 64 + lane;
    const int cb = (wave >> 1) * 16;       // k (cin) base, 16 per thread
    const float* xp = xb + (size_t)(ks * 32 + cb) * N_TOK + j;
    u16 vals[16];
#pragma unroll
    for (int qq = 0; qq < 16; ++qq) vals[qq] = f2bf(xp[(size_t)qq * N_TOK]);
    const int swz = (j >> 1) & 3;
    u16* row = xtb + j * 32;
    const int c0 = cb >> 3;
    *(short8*)&row[((c0    ) ^ swz) * 8] = *(const short8*)&vals[0];
    *(short8*)&row[((c0 + 1) ^ swz) * 8] = *(const short8*)&vals[8];
}

__global__ __launch_bounds__(256, 2) void v_proj(
    const float* __restrict__ x2,
    const float* __restrict__ wv1, const float* __restrict__ bv1,
    const float* __restrict__ wv2, const float* __restrict__ bv2,
    u8* __restrict__ wsV)
{
    __shared__ __align__(16) u16 wl[128 * 256];     // [c][k] swizzled, 64 KB
    __shared__ __align__(16) u16 xt[2][128 * 32];   // [j][k] swizzled, 16 KB

    const int jt = blockIdx.x, ct = blockIdx.y, s = blockIdx.z;
    const int branch = s >> 2, b = s & 3;
    const float* w    = branch ? wv2 : wv1;
    const float* bias = branch ? bv2 : bv1;
    u8* dstB = wsV + (size_t)s * N_TOK * C_DIM;     // packed fp8 slice (1 MB)
    const float* xb = x2 + (size_t)b * C_DIM * N_TOK + jt * 128;

    const int tid = threadIdx.x;
    const int wave = tid >> 6, lane = tid & 63;
    const int wr = wave >> 1, wc = wave & 1;
    const int g = lane >> 4, li = lane & 15;

    // ---- stage W[128c][256k] -> bf16 LDS, chunk kc at pos kc ^ (c&7)
    {
        const int c = tid >> 1;
        const int kh = (tid & 1) * 128;
        const float* wrow = w + (size_t)(ct * 128 + c) * C_DIM + kh;
        u16* lrow = wl + c * 256;
#pragma unroll
        for (int kk = 0; kk < 128; kk += 8) {
            const float4 a0 = *(const float4*)&wrow[kk];
            const float4 a1 = *(const float4*)&wrow[kk + 4];
            u16 tmp[8] = {f2bf(a0.x), f2bf(a0.y), f2bf(a0.z), f2bf(a0.w),
                          f2bf(a1.x), f2bf(a1.y), f2bf(a1.z), f2bf(a1.w)};
            const int kc = (kh + kk) >> 3;
            *(short8*)&lrow[(kc ^ (c & 7)) * 8] = *(const short8*)tmp;
        }
    }
    stage_xt(&xt[0][0], xb, 0, wave, lane);
    __syncthreads();

    f32x4 acc[4][4];
#pragma unroll
    for (int mf = 0; mf < 4; ++mf)
#pragma unroll
        for (int nf = 0; nf < 4; ++nf) acc[mf][nf] = (f32x4){0.f, 0.f, 0.f, 0.f};

    int buf = 0;
    for (int ks = 0; ks < 8; ++ks) {
        if (ks < 7) stage_xt(&xt[buf ^ 1][0], xb, ks + 1, wave, lane);

        short8 af[4], bf[4];
#pragma unroll
        for (int mf = 0; mf < 4; ++mf) {
            const int c = wr * 64 + mf * 16 + li;
            af[mf] = *(const short8*)&wl[c * 256 + (((ks * 4 + g) ^ (li & 7)) * 8)];
        }
#pragma unroll
        for (int nf = 0; nf < 4; ++nf) {
            const int j = wc * 64 + nf * 16 + li;
            bf[nf] = *(const short8*)&xt[buf][j * 32 + ((g ^ ((j >> 1) & 3)) * 8)];
        }
        __builtin_amdgcn_s_setprio(1);
#pragma unroll
        for (int mf = 0; mf < 4; ++mf)
#pragma unroll
            for (int nf = 0; nf < 4; ++nf)
                acc[mf][nf] = __builtin_amdgcn_mfma_f32_16x16x32_bf16(
                    af[mf], bf[nf], acc[mf][nf], 0, 0, 0);
        __builtin_amdgcn_s_setprio(0);
        __syncthreads();
        buf ^= 1;
    }

    // ---- epilogue: write packed fp8 V
#pragma unroll
    for (int mf = 0; mf < 4; ++mf) {
#pragma unroll
        for (int r = 0; r < 4; ++r) {
            const int c = ct * 128 + wr * 64 + mf * 16 + 4 * g + r;
            const float bv = bias[c];
#pragma unroll
            for (int nf = 0; nf < 4; ++nf) {
                const int j = jt * 128 + wc * 64 + nf * 16 + li;
                dstB[(size_t)(j >> 5) * 8192 + ((j >> 3) & 3) * 2048
                     + c * 8 + (j & 7)] = f2fp8(acc[mf][nf][r] + bv);
            }
        }
    }
}

// ---------------------------------------------------------------------------
// Kernel 3: flash attention, static-max exp2 softmax, c-split, fp8 PV,
// 4-way j-split.  block 512 = 8 waves = 4 grp (j-quarters) x 2 wg (i-halves);
// R=2, acc[2][8] = 64 VGPRs.  __launch_bounds__(512, 4): cap 128 VGPR --
// natural allocation ~64 lets HW run 8 waves/SIMD (LDS 36.9KB -> 4 blocks/CU).
// (Round 16's (512,8) forced a 32-VGPR cap -> total spill, 1.5GB scratch.)
// Merge: 2-round tree (grp1->0, grp3->2, then 2->0) via vlds scratch.
// grid 1024: n = slice + 8*(ib + 64*ct); slice = n%8 -> XCD affinity.
// ---------------------------------------------------------------------------
__global__ __launch_bounds__(512, 4) void attn_fwd(
    const u16* __restrict__ Q, const u16* __restrict__ K,
    const u8* __restrict__ V, u16* __restrict__ O)
{
    __shared__ __align__(16) u8 vlds[4][2][4096];   // [grp][buf] 32 KB
    __shared__ float lscr[4][2][64][2];             // [grp][wg][lane][it] 4 KB

    const int n  = blockIdx.x;
    const int s  = n & 7;              // slice -> XCD (n%8)
    const int ib = (n >> 3) & 63;      // i-block of 64 rows
    const int ct = n >> 9;             // c-half
    const u16* q = Q + (size_t)s * N_TOK * D_DIM;
    const u16* k = K + (size_t)s * N_TOK * D_DIM;
    const u8*  v = V + (size_t)s * N_TOK * C_DIM + ct * 1024;  // c-half in p-chunks
    u16*       o = O + (size_t)s * N_TOK * C_DIM + ct * 128;

    const int tid  = threadIdx.x;
    const int wave = tid >> 6;
    const int lane = tid & 63;
    const int grp  = wave >> 1;        // j-quarter (0..3)
    const int wg   = wave & 1;         // i-half
    const int g    = lane >> 4;
    const int li   = lane & 15;
    const int i0   = ib * 64 + wg * 32;
    const int jbase = grp * (N_TOK / 4);
    const int NP = N_TOK / 4 / 32;     // 32 periods of 32 j

    short8 qf[2];
    qf[0] = *(const short8*)(q + (size_t)(i0 + li) * D_DIM + 8 * g);
    qf[1] = *(const short8*)(q + (size_t)(i0 + 16 + li) * D_DIM + 8 * g);

    f32x4 acc[2][8];
#pragma unroll
    for (int it = 0; it < 2; ++it)
#pragma unroll
        for (int cf = 0; cf < 8; ++cf) acc[it][cf] = (f32x4){0.f, 0.f, 0.f, 0.f};
    float lsum[2] = {0.f, 0.f};

    // prologue: V tile 0 (2 x 1KB linear chunks per wave) + K(0)
    {
        const u8* tile = v + (size_t)(jbase >> 5) * 8192;
#pragma unroll
        for (int ii = 0; ii < 2; ++ii) {
            const int pc = wg * 2 + ii;
            __builtin_amdgcn_global_load_lds(
                (const __attribute__((address_space(1))) void*)(tile + pc * 2048 + lane * 16),
                (__attribute__((address_space(3))) void*)(&vlds[grp][0][0] + pc * 1024),
                16, 0, 0);
        }
    }
    __syncthreads();

    int buf = 0;
    for (int p = 0; p < NP; ++p) {
        if (p < NP - 1) {               // stage next V tile (async)
            const u8* tile = v + (size_t)((jbase + (p + 1) * 32) >> 5) * 8192;
            u8* dst = &vlds[grp][buf ^ 1][0];
#pragma unroll
            for (int ii = 0; ii < 2; ++ii) {
                const int pc = wg * 2 + ii;
                __builtin_amdgcn_global_load_lds(
                    (const __attribute__((address_space(1))) void*)(tile + pc * 2048 + lane * 16),
                    (__attribute__((address_space(3))) void*)(dst + pc * 1024),
                    16, 0, 0);
            }
        }

        // K fragments for this period (L2-resident; TLP hides latency)
        const int j0 = jbase + p * 32;
        const short8 ke = *(const short8*)(k + (size_t)(j0 + 2 * li    ) * D_DIM + 8 * g);
        const short8 ko = *(const short8*)(k + (size_t)(j0 + 2 * li + 1) * D_DIM + 8 * g);

        const f32x4 z = (f32x4){0.f, 0.f, 0.f, 0.f};
        i64 paL[2];
#pragma unroll
        for (int it = 0; it < 2; ++it) {
            f32x4 se = __builtin_amdgcn_mfma_f32_16x16x32_bf16(ke, qf[it], z, 0, 0, 0);
            f32x4 so = __builtin_amdgcn_mfma_f32_16x16x32_bf16(ko, qf[it], z, 0, 0, 0);
            float pe[4], po[4];
#pragma unroll
            for (int r = 0; r < 4; ++r) {
                pe[r] = exp2_fast(se[r]);   // P = 2^(s*log2e), static shift
                po[r] = exp2_fast(so[r]);
            }
            lsum[it] += ((pe[0] + po[0]) + (pe[1] + po[1]))
                      + ((pe[2] + po[2]) + (pe[3] + po[3]));
            // pack P -> 8 fp8 bytes: byte e = j (8g+e); e=2r even (pe), 2r+1 odd (po)
            int w0 = pk_fp8<false>(pe[0], po[0], 0);
            w0     = pk_fp8<true >(pe[1], po[1], w0);
            int w1 = pk_fp8<false>(pe[2], po[2], 0);
            w1     = pk_fp8<true >(pe[3], po[3], w1);
            paL[it] = (i64)(((unsigned long long)(unsigned)w1 << 32) | (unsigned)w0);
        }

        // O += P * V^T ; fp8 MFMA, one b64 V read feeds both i-tiles
        const u8* vb = &vlds[grp][buf][0];
        const i64* vbL = (const i64*)(vb + g * 1024 + li * 8);
        __builtin_amdgcn_s_setprio(1);
#pragma unroll
        for (int cf = 0; cf < 8; ++cf) {
            const i64 vfL = vbL[cf * 16];
            acc[0][cf] = __builtin_amdgcn_mfma_f32_16x16x32_fp8_fp8(paL[0], vfL, acc[0][cf], 0, 0, 0);
            acc[1][cf] = __builtin_amdgcn_mfma_f32_16x16x32_fp8_fp8(paL[1], vfL, acc[1][cf], 0, 0, 0);
        }
        __builtin_amdgcn_s_setprio(0);
        __syncthreads();
        buf ^= 1;
    }

    // ---- lsum publish (lane-reduced) ----
#pragma unroll
    for (int it = 0; it < 2; ++it) {
        lsum[it] += __shfl_xor(lsum[it], 16);
        lsum[it] += __shfl_xor(lsum[it], 32);
        lscr[grp][wg][lane][it] = lsum[it];
    }

    // ---- merge 4 j-quarter partials: 2-round tree, pure add ----
    f32x4* pv = (f32x4*)&vlds[0][0][0];   // 32 KB scratch (2048 f32x4)
#pragma unroll
    for (int it = 0; it < 2; ++it) {
        // round 1: grp1 -> grp0, grp3 -> grp2
        __syncthreads();
        if (grp & 1) {
#pragma unroll
            for (int cf = 0; cf < 8; ++cf)
                pv[(((grp >> 1) * 2 + wg) * 8 + cf) * 64 + lane] = acc[it][cf];
        }
        __syncthreads();
        if (!(grp & 1)) {
#pragma unroll
            for (int cf = 0; cf < 8; ++cf) {
                const f32x4 o4 = pv[(((grp >> 1) * 2 + wg) * 8 + cf) * 64 + lane];
                acc[it][cf][0] += o4[0]; acc[it][cf][1] += o4[1];
                acc[it][cf][2] += o4[2]; acc[it][cf][3] += o4[3];
            }
        }
        // round 2: grp2 -> grp0
        __syncthreads();
        if (grp == 2) {
#pragma unroll
            for (int cf = 0; cf < 8; ++cf)
                pv[(wg * 8 + cf) * 64 + lane] = acc[it][cf];
        }
        __syncthreads();
        if (grp == 0) {
#pragma unroll
            for (int cf = 0; cf < 8; ++cf) {
                const f32x4 o4 = pv[(wg * 8 + cf) * 64 + lane];
                acc[it][cf][0] += o4[0]; acc[it][cf][1] += o4[1];
                acc[it][cf][2] += o4[2]; acc[it][cf][3] += o4[3];
            }
        }
    }

    if (grp == 0) {
#pragma unroll
        for (int it = 0; it < 2; ++it) {
            const float linv = 1.0f /
                (lscr[0][wg][lane][it] + lscr[1][wg][lane][it] +
                 lscr[2][wg][lane][it] + lscr[3][wg][lane][it]);
            float lr[4];
#pragma unroll
            for (int r = 0; r < 4; ++r) lr[r] = __shfl(linv, 4 * g + r);
#pragma unroll
            for (int cf = 0; cf < 8; ++cf)
#pragma unroll
                for (int r = 0; r < 4; ++r)
                    o[(size_t)(i0 + it * 16 + 4 * g + r) * C_DIM + cf * 16 + li] =
                        f2bf(acc[it][cf][r] * lr[r]);
        }
    }
}

// ---------------------------------------------------------------------------
// Kernel 4: out[b][c][i] = x1 + x2 + O1[b][i][c] + O2[b][i][c]  (LDS transpose)
// ---------------------------------------------------------------------------
__global__ __launch_bounds__(256) void epilogue(
    const float* __restrict__ x1, const float* __restrict__ x2,
    const u16* __restrict__ O, float* __restrict__ out)
{
    __shared__ float tl[64][65];
    const int it = blockIdx.x, ct = blockIdx.y, b = blockIdx.z;
    const int tid = threadIdx.x;
    const int cl = tid & 63, r0 = tid >> 6;

    const u16* O1 = O + (size_t)(b)     * N_TOK * C_DIM;
    const u16* O2 = O + (size_t)(4 + b) * N_TOK * C_DIM;

#pragma unroll
    for (int rr = 0; rr < 16; ++rr) {
        const int il = r0 + rr * 4;
        const size_t off = (size_t)(it * 64 + il) * C_DIM + ct * 64 + cl;
        tl[il][cl] = bf2f(O1[off]) + bf2f(O2[off]);
    }
    __syncthreads();
#pragma unroll
    for (int rr = 0; rr < 16; ++rr) {
        const int c2 = r0 + rr * 4;
        const size_t idx = ((size_t)b * C_DIM + ct * 64 + c2) * N_TOK + it * 64 + cl;
        out[idx] = x1[idx] + x2[idx] + tl[cl][c2];
    }
}

// ---------------------------------------------------------------------------
extern "C" void kernel_launch(void* const* d_in, const int* in_sizes, int n_in,
                              void* d_out, int out_size, void* d_ws, size_t ws_size,
                              hipStream_t stream)
{
    const float* x1  = (const float*)d_in[0];
    const float* x2  = (const float*)d_in[1];
    const float* wq1 = (const float*)d_in[2];
    const float* bq1 = (const float*)d_in[3];
    const float* wk1 = (const float*)d_in[4];
    const float* bk1 = (const float*)d_in[5];
    const float* wv1 = (const float*)d_in[6];
    const float* bv1 = (const float*)d_in[7];
    const float* wq2 = (const float*)d_in[8];
    const float* bq2 = (const float*)d_in[9];
    const float* wk2 = (const float*)d_in[10];
    const float* bk2 = (const float*)d_in[11];
    const float* wv2 = (const float*)d_in[12];
    const float* bv2 = (const float*)d_in[13];
    float* out = (float*)d_out;

    // ws layout: Q bf16 2MB | K bf16 2MB | V fp8 packed 8MB | O bf16 16MB
    u16* wsQ = (u16*)d_ws;
    u16* wsK = wsQ + (size_t)8 * N_TOK * D_DIM;
    u8*  wsV = (u8*)(wsK + (size_t)8 * N_TOK * D_DIM);
    u16* wsO = (u16*)(wsV + (size_t)8 * N_TOK * C_DIM);

    qk_proj<<<dim3(64, 16), 256, 0, stream>>>(x1, x2, wq1, bq1, wk1, bk1,
                                              wq2, bq2, wk2, bk2, wsQ, wsK);
    v_proj<<<dim3(32, 2, 8), 256, 0, stream>>>(x2, wv1, bv1, wv2, bv2, wsV);
    attn_fwd<<<dim3(1024), 512, 0, stream>>>(wsQ, wsK, wsV, wsO);
    epilogue<<<dim3(64, 4, 4), 256, 0, stream>>>(x1, x2, wsO, out);
}

// Round 18
// 146.603 us; speedup vs baseline: 6.0925x; 1.0257x over previous
//
#include <hip/hip_runtime.h>
#include <hip/hip_fp8.h>

// Problem constants
#define N_TOK 4096   // H*W
#define C_DIM 256
#define D_DIM 32

typedef float f32x4 __attribute__((ext_vector_type(4)));
typedef short short8 __attribute__((ext_vector_type(8)));
typedef unsigned short u16;
typedef unsigned char u8;
typedef long long i64;

__device__ __forceinline__ u16 f2bf(float f) {
    unsigned int u = __builtin_bit_cast(unsigned int, f);
    u += 0x7fffu + ((u >> 16) & 1u);   // round-to-nearest-even
    return (u16)(u >> 16);
}
__device__ __forceinline__ float bf2f(u16 h) {
    unsigned int u = ((unsigned int)h) << 16;
    return __builtin_bit_cast(float, u);
}
__device__ __forceinline__ float exp2_fast(float x) {  // 2^x, compiler-managed
#if __has_builtin(__builtin_amdgcn_exp2f)
    return __builtin_amdgcn_exp2f(x);
#else
    return exp2f(x);
#endif
}
// pack 2 f32 -> 2 OCP e4m3 bytes into half of a dword (HI is compile-time)
template<bool HI>
__device__ __forceinline__ int pk_fp8(float a, float b, int old) {
#if __has_builtin(__builtin_amdgcn_cvt_pk_fp8_f32)
    return __builtin_amdgcn_cvt_pk_fp8_f32(a, b, old, HI);
#else
    __hip_fp8_e4m3 fa(a), fb(b);
    int v = (int)fa.__x | ((int)fb.__x << 8);
    return HI ? ((old & 0xffff) | (v << 16)) : ((old & ~0xffff) | (v & 0xffff));
#endif
}
__device__ __forceinline__ u8 f2fp8(float f) {
    return (u8)(pk_fp8<false>(f, f, 0) & 0xff);
}

// Packed V layout (fp8 e4m3 bytes), per slice (1 MB):
//   byte = jblk*8192 + p*2048 + c*8 + (j&7),  jblk = j>>5,  p = (j>>3)&3
// (jblk, p, c-half) chunk = contiguous 1 KB -> linear stage copy.

// ---------------------------------------------------------------------------
// Kernel 1: q/k projection.  q = (wq*x1 + bq)*log2e, k = wk*x2 + bk
// Output layout: Q[slice][i][d], K[slice][j][d]  (d contiguous, bf16)
// ---------------------------------------------------------------------------
__global__ __launch_bounds__(256) void qk_proj(
    const float* __restrict__ x1, const float* __restrict__ x2,
    const float* __restrict__ wq1, const float* __restrict__ bq1,
    const float* __restrict__ wk1, const float* __restrict__ bk1,
    const float* __restrict__ wq2, const float* __restrict__ bq2,
    const float* __restrict__ wk2, const float* __restrict__ bk2,
    u16* __restrict__ wsQ, u16* __restrict__ wsK)
{
    __shared__ float w_lds[32 * 256];
    const int ib = blockIdx.x;
    const int comb = blockIdx.y;
    const int b = comb & 3;
    const int branch = (comb >> 2) & 1;
    const int qk = comb >> 3;

    const float* x = qk ? x2 : x1;           // q from x1; k from x2
    const float* w; const float* bias; u16* dst;
    if (qk == 0) { w = branch ? wq2 : wq1; bias = branch ? bq2 : bq1; dst = wsQ; }
    else         { w = branch ? wk2 : wk1; bias = branch ? bk2 : bk1; dst = wsK; }
    const int slice = branch * 4 + b;
    dst += (size_t)slice * N_TOK * D_DIM;
    const float osc = (qk == 0) ? 1.44269504088896341f : 1.0f;

    const int tid = threadIdx.x;
    for (int t = tid; t < 32 * 256; t += 256) w_lds[t] = w[t];
    __syncthreads();

    const int il = tid & 63;
    const int db = tid >> 6;                 // 0..3 -> d = db*8 + mm
    const float* xc = x + (size_t)b * C_DIM * N_TOK + ib * 64 + il;

    float acc[8] = {0.f,0.f,0.f,0.f,0.f,0.f,0.f,0.f};
    for (int c4 = 0; c4 < 256; c4 += 4) {
        const float xv0 = xc[(size_t)(c4 + 0) * N_TOK];
        const float xv1 = xc[(size_t)(c4 + 1) * N_TOK];
        const float xv2 = xc[(size_t)(c4 + 2) * N_TOK];
        const float xv3 = xc[(size_t)(c4 + 3) * N_TOK];
#pragma unroll
        for (int mm = 0; mm < 8; ++mm) {
            const float4 wv = *(const float4*)&w_lds[(db * 8 + mm) * 256 + c4];
            acc[mm] += xv0 * wv.x + xv1 * wv.y + xv2 * wv.z + xv3 * wv.w;
        }
    }
    short8 pack;
#pragma unroll
    for (int mm = 0; mm < 8; ++mm)
        pack[mm] = (short)f2bf((acc[mm] + bias[db * 8 + mm]) * osc);
    *(short8*)(dst + (size_t)(ib * 64 + il) * D_DIM + db * 8) = pack;
}

// ---------------------------------------------------------------------------
// Kernel 2: v projection via MFMA, writing PACKED fp8 V.
// block 256 (4 waves, 2x2 wave grid), tile 128c x 128j, K=256 in 8 steps.
// grid (32 jt, 2 ct, 8 slices)
// ---------------------------------------------------------------------------
__device__ __forceinline__ void stage_xt(u16* xtb, const float* xb, int ks,
                                         int wave, int lane)
{
    // XT[j][k] (32 k per buf, 64B rows), chunk kc stored at pos kc ^ ((j>>1)&3)
    const int j  = (wave & 1) * 64 + lane;
    const int cb = (wave >> 1) * 16;       // k (cin) base, 16 per thread
    const float* xp = xb + (size_t)(ks * 32 + cb) * N_TOK + j;
    u16 vals[16];
#pragma unroll
    for (int qq = 0; qq < 16; ++qq) vals[qq] = f2bf(xp[(size_t)qq * N_TOK]);
    const int swz = (j >> 1) & 3;
    u16* row = xtb + j * 32;
    const int c0 = cb >> 3;
    *(short8*)&row[((c0    ) ^ swz) * 8] = *(const short8*)&vals[0];
    *(short8*)&row[((c0 + 1) ^ swz) * 8] = *(const short8*)&vals[8];
}

__global__ __launch_bounds__(256, 2) void v_proj(
    const float* __restrict__ x2,
    const float* __restrict__ wv1, const float* __restrict__ bv1,
    const float* __restrict__ wv2, const float* __restrict__ bv2,
    u8* __restrict__ wsV)
{
    __shared__ __align__(16) u16 wl[128 * 256];     // [c][k] swizzled, 64 KB
    __shared__ __align__(16) u16 xt[2][128 * 32];   // [j][k] swizzled, 16 KB

    const int jt = blockIdx.x, ct = blockIdx.y, s = blockIdx.z;
    const int branch = s >> 2, b = s & 3;
    const float* w    = branch ? wv2 : wv1;
    const float* bias = branch ? bv2 : bv1;
    u8* dstB = wsV + (size_t)s * N_TOK * C_DIM;     // packed fp8 slice (1 MB)
    const float* xb = x2 + (size_t)b * C_DIM * N_TOK + jt * 128;

    const int tid = threadIdx.x;
    const int wave = tid >> 6, lane = tid & 63;
    const int wr = wave >> 1, wc = wave & 1;
    const int g = lane >> 4, li = lane & 15;

    // ---- stage W[128c][256k] -> bf16 LDS, chunk kc at pos kc ^ (c&7)
    {
        const int c = tid >> 1;
        const int kh = (tid & 1) * 128;
        const float* wrow = w + (size_t)(ct * 128 + c) * C_DIM + kh;
        u16* lrow = wl + c * 256;
#pragma unroll
        for (int kk = 0; kk < 128; kk += 8) {
            const float4 a0 = *(const float4*)&wrow[kk];
            const float4 a1 = *(const float4*)&wrow[kk + 4];
            u16 tmp[8] = {f2bf(a0.x), f2bf(a0.y), f2bf(a0.z), f2bf(a0.w),
                          f2bf(a1.x), f2bf(a1.y), f2bf(a1.z), f2bf(a1.w)};
            const int kc = (kh + kk) >> 3;
            *(short8*)&lrow[(kc ^ (c & 7)) * 8] = *(const short8*)tmp;
        }
    }
    stage_xt(&xt[0][0], xb, 0, wave, lane);
    __syncthreads();

    f32x4 acc[4][4];
#pragma unroll
    for (int mf = 0; mf < 4; ++mf)
#pragma unroll
        for (int nf = 0; nf < 4; ++nf) acc[mf][nf] = (f32x4){0.f, 0.f, 0.f, 0.f};

    int buf = 0;
    for (int ks = 0; ks < 8; ++ks) {
        if (ks < 7) stage_xt(&xt[buf ^ 1][0], xb, ks + 1, wave, lane);

        short8 af[4], bf[4];
#pragma unroll
        for (int mf = 0; mf < 4; ++mf) {
            const int c = wr * 64 + mf * 16 + li;
            af[mf] = *(const short8*)&wl[c * 256 + (((ks * 4 + g) ^ (li & 7)) * 8)];
        }
#pragma unroll
        for (int nf = 0; nf < 4; ++nf) {
            const int j = wc * 64 + nf * 16 + li;
            bf[nf] = *(const short8*)&xt[buf][j * 32 + ((g ^ ((j >> 1) & 3)) * 8)];
        }
        __builtin_amdgcn_s_setprio(1);
#pragma unroll
        for (int mf = 0; mf < 4; ++mf)
#pragma unroll
            for (int nf = 0; nf < 4; ++nf)
                acc[mf][nf] = __builtin_amdgcn_mfma_f32_16x16x32_bf16(
                    af[mf], bf[nf], acc[mf][nf], 0, 0, 0);
        __builtin_amdgcn_s_setprio(0);
        __syncthreads();
        buf ^= 1;
    }

    // ---- epilogue: write packed fp8 V
#pragma unroll
    for (int mf = 0; mf < 4; ++mf) {
#pragma unroll
        for (int r = 0; r < 4; ++r) {
            const int c = ct * 128 + wr * 64 + mf * 16 + 4 * g + r;
            const float bv = bias[c];
#pragma unroll
            for (int nf = 0; nf < 4; ++nf) {
                const int j = jt * 128 + wc * 64 + nf * 16 + li;
                dstB[(size_t)(j >> 5) * 8192 + ((j >> 3) & 3) * 2048
                     + c * 8 + (j & 7)] = f2fp8(acc[mf][nf][r] + bv);
            }
        }
    }
}

// ---------------------------------------------------------------------------
// Kernel 3: flash attention, static-max exp2 softmax, c-split, fp8 PV,
// KVBLK=64 (two 32-j subtiles per period): one barrier + one stage batch +
// one K batch per 64 j -> per-period fixed cost (barrier drain, chain
// startup) paid 32x instead of 64x.  Inner 32-j body identical to round 12.
// block 256 = 4 waves = 2 grp (j-halves) x 2 wg (i-halves); R=2; acc[2][8].
// Incremental kp/vtile pointers (constant stride) cut per-period addr VALU.
// grid 1024: n = slice + 8*(ib + 64*ct); slice = n%8 -> XCD affinity.
// ---------------------------------------------------------------------------
__global__ __launch_bounds__(256, 4) void attn_fwd(
    const u16* __restrict__ Q, const u16* __restrict__ K,
    const u8* __restrict__ V, u16* __restrict__ O)
{
    __shared__ __align__(16) u8 vlds[2][2][2][4096];  // [grp][buf][jsub] 32 KB
    __shared__ float lscr[2][2][64][2];               // [grp][wg][lane][it]

    const int n  = blockIdx.x;
    const int s  = n & 7;              // slice -> XCD (n%8)
    const int ib = (n >> 3) & 63;      // i-block of 64 rows
    const int ct = n >> 9;             // c-half
    const u16* q = Q + (size_t)s * N_TOK * D_DIM;
    const u16* k = K + (size_t)s * N_TOK * D_DIM;
    const u8*  v = V + (size_t)s * N_TOK * C_DIM + ct * 1024;  // c-half in p-chunks
    u16*       o = O + (size_t)s * N_TOK * C_DIM + ct * 128;

    const int tid  = threadIdx.x;
    const int wave = tid >> 6;
    const int lane = tid & 63;
    const int grp  = wave >> 1;        // j-half
    const int wg   = wave & 1;         // i-half
    const int g    = lane >> 4;
    const int li   = lane & 15;
    const int i0   = ib * 64 + wg * 32;
    const int jbase = grp * (N_TOK / 2);
    const int NP = N_TOK / 2 / 64;     // 32 periods of 64 j

    short8 qf[2];
    qf[0] = *(const short8*)(q + (size_t)(i0 + li) * D_DIM + 8 * g);
    qf[1] = *(const short8*)(q + (size_t)(i0 + 16 + li) * D_DIM + 8 * g);

    f32x4 acc[2][8];
#pragma unroll
    for (int it = 0; it < 2; ++it)
#pragma unroll
        for (int cf = 0; cf < 8; ++cf) acc[it][cf] = (f32x4){0.f, 0.f, 0.f, 0.f};
    float lsum[2] = {0.f, 0.f};

    // incremental pointers (constant stride per period)
    const u8*  vtile = v + (size_t)(jbase >> 5) * 8192;  // +16384 B / period
    const u16* kp    = k + (size_t)jbase * D_DIM;        // +64 rows / period

    // prologue: stage period-0 tile (2 jsubs x 2 chunks per wave)
#pragma unroll
    for (int jsub = 0; jsub < 2; ++jsub)
#pragma unroll
        for (int ii = 0; ii < 2; ++ii) {
            const int pc = wg * 2 + ii;
            __builtin_amdgcn_global_load_lds(
                (const __attribute__((address_space(1))) void*)
                    (vtile + jsub * 8192 + pc * 2048 + lane * 16),
                (__attribute__((address_space(3))) void*)
                    (&vlds[grp][0][jsub][pc * 1024]),
                16, 0, 0);
        }
    __syncthreads();

    int buf = 0;
    for (int p = 0; p < NP; ++p) {
        if (p < NP - 1) {               // stage next 64-j tile (async)
            const u8* nt = vtile + 16384;
#pragma unroll
            for (int jsub = 0; jsub < 2; ++jsub)
#pragma unroll
                for (int ii = 0; ii < 2; ++ii) {
                    const int pc = wg * 2 + ii;
                    __builtin_amdgcn_global_load_lds(
                        (const __attribute__((address_space(1))) void*)
                            (nt + jsub * 8192 + pc * 2048 + lane * 16),
                        (__attribute__((address_space(3))) void*)
                            (&vlds[grp][buf ^ 1][jsub][pc * 1024]),
                        16, 0, 0);
                }
        }

        // K fragments for both jsubs (L2-resident; TLP hides latency)
        const short8 ke0 = *(const short8*)(kp + (size_t)(2 * li     ) * D_DIM + 8 * g);
        const short8 ko0 = *(const short8*)(kp + (size_t)(2 * li + 1 ) * D_DIM + 8 * g);
        const short8 ke1 = *(const short8*)(kp + (size_t)(32 + 2 * li) * D_DIM + 8 * g);
        const short8 ko1 = *(const short8*)(kp + (size_t)(33 + 2 * li) * D_DIM + 8 * g);

        const f32x4 z = (f32x4){0.f, 0.f, 0.f, 0.f};
#pragma unroll
        for (int jsub = 0; jsub < 2; ++jsub) {
            const short8 ke = jsub ? ke1 : ke0;
            const short8 ko = jsub ? ko1 : ko0;
            i64 paL[2];
#pragma unroll
            for (int it = 0; it < 2; ++it) {
                f32x4 se = __builtin_amdgcn_mfma_f32_16x16x32_bf16(ke, qf[it], z, 0, 0, 0);
                f32x4 so = __builtin_amdgcn_mfma_f32_16x16x32_bf16(ko, qf[it], z, 0, 0, 0);
                float pe[4], po[4];
#pragma unroll
                for (int r = 0; r < 4; ++r) {
                    pe[r] = exp2_fast(se[r]);   // P = 2^(s*log2e), static shift
                    po[r] = exp2_fast(so[r]);
                }
                lsum[it] += ((pe[0] + po[0]) + (pe[1] + po[1]))
                          + ((pe[2] + po[2]) + (pe[3] + po[3]));
                int w0 = pk_fp8<false>(pe[0], po[0], 0);
                w0     = pk_fp8<true >(pe[1], po[1], w0);
                int w1 = pk_fp8<false>(pe[2], po[2], 0);
                w1     = pk_fp8<true >(pe[3], po[3], w1);
                paL[it] = (i64)(((unsigned long long)(unsigned)w1 << 32) | (unsigned)w0);
            }

            // O += P * V^T ; fp8 MFMA, one b64 V read feeds both i-tiles
            const u8* vb = &vlds[grp][buf][jsub][0];
            const i64* vbL = (const i64*)(vb + g * 1024 + li * 8);
#pragma unroll
            for (int cf = 0; cf < 8; ++cf) {
                const i64 vfL = vbL[cf * 16];
                acc[0][cf] = __builtin_amdgcn_mfma_f32_16x16x32_fp8_fp8(paL[0], vfL, acc[0][cf], 0, 0, 0);
                acc[1][cf] = __builtin_amdgcn_mfma_f32_16x16x32_fp8_fp8(paL[1], vfL, acc[1][cf], 0, 0, 0);
            }
        }
        __syncthreads();
        buf ^= 1;
        vtile += 16384;
        kp    += 64 * D_DIM;
    }

    // ---- merge the 2 j-half partials: pure add (static-max => same scale) ----
#pragma unroll
    for (int it = 0; it < 2; ++it) {
        lsum[it] += __shfl_xor(lsum[it], 16);
        lsum[it] += __shfl_xor(lsum[it], 32);
        lscr[grp][wg][lane][it] = lsum[it];
    }

    f32x4* pv = (f32x4*)&vlds[0][0][0][0];   // reuse 32 KB as merge scratch
#pragma unroll
    for (int it = 0; it < 2; ++it) {
        __syncthreads();
        if (grp == 1) {
#pragma unroll
            for (int cf = 0; cf < 8; ++cf)
                pv[(wg * 8 + cf) * 64 + lane] = acc[it][cf];
        }
        __syncthreads();
        if (grp == 0) {
#pragma unroll
            for (int cf = 0; cf < 8; ++cf) {
                const f32x4 o4 = pv[(wg * 8 + cf) * 64 + lane];
                acc[it][cf][0] += o4[0]; acc[it][cf][1] += o4[1];
                acc[it][cf][2] += o4[2]; acc[it][cf][3] += o4[3];
            }
        }
    }

    if (grp == 0) {
#pragma unroll
        for (int it = 0; it < 2; ++it) {
            const float linv = 1.0f / (lscr[0][wg][lane][it] + lscr[1][wg][lane][it]);
            float lr[4];
#pragma unroll
            for (int r = 0; r < 4; ++r) lr[r] = __shfl(linv, 4 * g + r);
#pragma unroll
            for (int cf = 0; cf < 8; ++cf)
#pragma unroll
                for (int r = 0; r < 4; ++r)
                    o[(size_t)(i0 + it * 16 + 4 * g + r) * C_DIM + cf * 16 + li] =
                        f2bf(acc[it][cf][r] * lr[r]);
        }
    }
}

// ---------------------------------------------------------------------------
// Kernel 4: out[b][c][i] = x1 + x2 + O1[b][i][c] + O2[b][i][c]  (LDS transpose)
// ---------------------------------------------------------------------------
__global__ __launch_bounds__(256) void epilogue(
    const float* __restrict__ x1, const float* __restrict__ x2,
    const u16* __restrict__ O, float* __restrict__ out)
{
    __shared__ float tl[64][65];
    const int it = blockIdx.x, ct = blockIdx.y, b = blockIdx.z;
    const int tid = threadIdx.x;
    const int cl = tid & 63, r0 = tid >> 6;

    const u16* O1 = O + (size_t)(b)     * N_TOK * C_DIM;
    const u16* O2 = O + (size_t)(4 + b) * N_TOK * C_DIM;

#pragma unroll
    for (int rr = 0; rr < 16; ++rr) {
        const int il = r0 + rr * 4;
        const size_t off = (size_t)(it * 64 + il) * C_DIM + ct * 64 + cl;
        tl[il][cl] = bf2f(O1[off]) + bf2f(O2[off]);
    }
    __syncthreads();
#pragma unroll
    for (int rr = 0; rr < 16; ++rr) {
        const int c2 = r0 + rr * 4;
        const size_t idx = ((size_t)b * C_DIM + ct * 64 + c2) * N_TOK + it * 64 + cl;
        out[idx] = x1[idx] + x2[idx] + tl[cl][c2];
    }
}

// ---------------------------------------------------------------------------
extern "C" void kernel_launch(void* const* d_in, const int* in_sizes, int n_in,
                              void* d_out, int out_size, void* d_ws, size_t ws_size,
                              hipStream_t stream)
{
    const float* x1  = (const float*)d_in[0];
    const float* x2  = (const float*)d_in[1];
    const float* wq1 = (const float*)d_in[2];
    const float* bq1 = (const float*)d_in[3];
    const float* wk1 = (const float*)d_in[4];
    const float* bk1 = (const float*)d_in[5];
    const float* wv1 = (const float*)d_in[6];
    const float* bv1 = (const float*)d_in[7];
    const float* wq2 = (const float*)d_in[8];
    const float* bq2 = (const float*)d_in[9];
    const float* wk2 = (const float*)d_in[10];
    const float* bk2 = (const float*)d_in[11];
    const float* wv2 = (const float*)d_in[12];
    const float* bv2 = (const float*)d_in[13];
    float* out = (float*)d_out;

    // ws layout: Q bf16 2MB | K bf16 2MB | V fp8 packed 8MB | O bf16 16MB
    u16* wsQ = (u16*)d_ws;
    u16* wsK = wsQ + (size_t)8 * N_TOK * D_DIM;
    u8*  wsV = (u8*)(wsK + (size_t)8 * N_TOK * D_DIM);
    u16* wsO = (u16*)(wsV + (size_t)8 * N_TOK * C_DIM);

    qk_proj<<<dim3(64, 16), 256, 0, stream>>>(x1, x2, wq1, bq1, wk1, bk1,
                                              wq2, bq2, wk2, bk2, wsQ, wsK);
    v_proj<<<dim3(32, 2, 8), 256, 0, stream>>>(x2, wv1, bv1, wv2, bv2, wsV);
    attn_fwd<<<dim3(1024), 256, 0, stream>>>(wsQ, wsK, wsV, wsO);
    epilogue<<<dim3(64, 4, 4), 256, 0, stream>>>(x1, x2, wsO, out);
}

// Round 19
// 139.599 us; speedup vs baseline: 6.3982x; 1.0502x over previous
//
#include <hip/hip_runtime.h>
#include <hip/hip_fp8.h>

// Problem constants
#define N_TOK 4096   // H*W
#define C_DIM 256
#define D_DIM 32

typedef float f32x4 __attribute__((ext_vector_type(4)));
typedef short short8 __attribute__((ext_vector_type(8)));
typedef unsigned short u16;
typedef unsigned char u8;
typedef long long i64;

__device__ __forceinline__ u16 f2bf(float f) {
    unsigned int u = __builtin_bit_cast(unsigned int, f);
    u += 0x7fffu + ((u >> 16) & 1u);   // round-to-nearest-even
    return (u16)(u >> 16);
}
__device__ __forceinline__ float bf2f(u16 h) {
    unsigned int u = ((unsigned int)h) << 16;
    return __builtin_bit_cast(float, u);
}
__device__ __forceinline__ float exp2_fast(float x) {  // 2^x, compiler-managed
#if __has_builtin(__builtin_amdgcn_exp2f)
    return __builtin_amdgcn_exp2f(x);
#else
    return exp2f(x);
#endif
}
// pack 2 f32 -> 2 OCP e4m3 bytes into half of a dword (HI is compile-time)
template<bool HI>
__device__ __forceinline__ int pk_fp8(float a, float b, int old) {
#if __has_builtin(__builtin_amdgcn_cvt_pk_fp8_f32)
    return __builtin_amdgcn_cvt_pk_fp8_f32(a, b, old, HI);
#else
    __hip_fp8_e4m3 fa(a), fb(b);
    int v = (int)fa.__x | ((int)fb.__x << 8);
    return HI ? ((old & 0xffff) | (v << 16)) : ((old & ~0xffff) | (v & 0xffff));
#endif
}
__device__ __forceinline__ u8 f2fp8(float f) {
    return (u8)(pk_fp8<false>(f, f, 0) & 0xff);
}

// Packed V layout (fp8 e4m3 bytes), per slice (1 MB):
//   byte = jblk*8192 + p*2048 + c*8 + (j&7),  jblk = j>>5,  p = (j>>3)&3
// p outermost => PV b64 reads hit each bank exactly 4x (structural minimum);
// a (jblk, p, c-half) chunk is a contiguous 1 KB -> linear stage copy.

// ---------------------------------------------------------------------------
// Kernel 1: q/k projection.  q = (wq*x1 + bq)*log2e, k = wk*x2 + bk
// Output layout: Q[slice][i][d], K[slice][j][d]  (d contiguous, bf16)
// ---------------------------------------------------------------------------
__global__ __launch_bounds__(256) void qk_proj(
    const float* __restrict__ x1, const float* __restrict__ x2,
    const float* __restrict__ wq1, const float* __restrict__ bq1,
    const float* __restrict__ wk1, const float* __restrict__ bk1,
    const float* __restrict__ wq2, const float* __restrict__ bq2,
    const float* __restrict__ wk2, const float* __restrict__ bk2,
    u16* __restrict__ wsQ, u16* __restrict__ wsK)
{
    __shared__ float w_lds[32 * 256];
    const int ib = blockIdx.x;
    const int comb = blockIdx.y;
    const int b = comb & 3;
    const int branch = (comb >> 2) & 1;
    const int qk = comb >> 3;

    const float* x = qk ? x2 : x1;           // q from x1; k from x2
    const float* w; const float* bias; u16* dst;
    if (qk == 0) { w = branch ? wq2 : wq1; bias = branch ? bq2 : bq1; dst = wsQ; }
    else         { w = branch ? wk2 : wk1; bias = branch ? bk2 : bk1; dst = wsK; }
    const int slice = branch * 4 + b;
    dst += (size_t)slice * N_TOK * D_DIM;
    const float osc = (qk == 0) ? 1.44269504088896341f : 1.0f;

    const int tid = threadIdx.x;
    for (int t = tid; t < 32 * 256; t += 256) w_lds[t] = w[t];
    __syncthreads();

    const int il = tid & 63;
    const int db = tid >> 6;                 // 0..3 -> d = db*8 + mm
    const float* xc = x + (size_t)b * C_DIM * N_TOK + ib * 64 + il;

    float acc[8] = {0.f,0.f,0.f,0.f,0.f,0.f,0.f,0.f};
    for (int c4 = 0; c4 < 256; c4 += 4) {
        const float xv0 = xc[(size_t)(c4 + 0) * N_TOK];
        const float xv1 = xc[(size_t)(c4 + 1) * N_TOK];
        const float xv2 = xc[(size_t)(c4 + 2) * N_TOK];
        const float xv3 = xc[(size_t)(c4 + 3) * N_TOK];
#pragma unroll
        for (int mm = 0; mm < 8; ++mm) {
            const float4 wv = *(const float4*)&w_lds[(db * 8 + mm) * 256 + c4];
            acc[mm] += xv0 * wv.x + xv1 * wv.y + xv2 * wv.z + xv3 * wv.w;
        }
    }
    short8 pack;
#pragma unroll
    for (int mm = 0; mm < 8; ++mm)
        pack[mm] = (short)f2bf((acc[mm] + bias[db * 8 + mm]) * osc);
    *(short8*)(dst + (size_t)(ib * 64 + il) * D_DIM + db * 8) = pack;
}

// ---------------------------------------------------------------------------
// Kernel 2: v projection via MFMA, writing PACKED fp8 V.
// block 256 (4 waves, 2x2 wave grid), tile 128c x 128j, K=256 in 8 steps.
// grid (32 jt, 2 ct, 8 slices)
// ---------------------------------------------------------------------------
__device__ __forceinline__ void stage_xt(u16* xtb, const float* xb, int ks,
                                         int wave, int lane)
{
    // XT[j][k] (32 k per buf, 64B rows), chunk kc stored at pos kc ^ ((j>>1)&3)
    const int j  = (wave & 1) * 64 + lane;
    const int cb = (wave >> 1) * 16;       // k (cin) base, 16 per thread
    const float* xp = xb + (size_t)(ks * 32 + cb) * N_TOK + j;
    u16 vals[16];
#pragma unroll
    for (int qq = 0; qq < 16; ++qq) vals[qq] = f2bf(xp[(size_t)qq * N_TOK]);
    const int swz = (j >> 1) & 3;
    u16* row = xtb + j * 32;
    const int c0 = cb >> 3;
    *(short8*)&row[((c0    ) ^ swz) * 8] = *(const short8*)&vals[0];
    *(short8*)&row[((c0 + 1) ^ swz) * 8] = *(const short8*)&vals[8];
}

__global__ __launch_bounds__(256, 2) void v_proj(
    const float* __restrict__ x2,
    const float* __restrict__ wv1, const float* __restrict__ bv1,
    const float* __restrict__ wv2, const float* __restrict__ bv2,
    u8* __restrict__ wsV)
{
    __shared__ __align__(16) u16 wl[128 * 256];     // [c][k] swizzled, 64 KB
    __shared__ __align__(16) u16 xt[2][128 * 32];   // [j][k] swizzled, 16 KB

    const int jt = blockIdx.x, ct = blockIdx.y, s = blockIdx.z;
    const int branch = s >> 2, b = s & 3;
    const float* w    = branch ? wv2 : wv1;
    const float* bias = branch ? bv2 : bv1;
    u8* dstB = wsV + (size_t)s * N_TOK * C_DIM;     // packed fp8 slice (1 MB)
    const float* xb = x2 + (size_t)b * C_DIM * N_TOK + jt * 128;

    const int tid = threadIdx.x;
    const int wave = tid >> 6, lane = tid & 63;
    const int wr = wave >> 1, wc = wave & 1;
    const int g = lane >> 4, li = lane & 15;

    // ---- stage W[128c][256k] -> bf16 LDS, chunk kc at pos kc ^ (c&7)
    {
        const int c = tid >> 1;
        const int kh = (tid & 1) * 128;
        const float* wrow = w + (size_t)(ct * 128 + c) * C_DIM + kh;
        u16* lrow = wl + c * 256;
#pragma unroll
        for (int kk = 0; kk < 128; kk += 8) {
            const float4 a0 = *(const float4*)&wrow[kk];
            const float4 a1 = *(const float4*)&wrow[kk + 4];
            u16 tmp[8] = {f2bf(a0.x), f2bf(a0.y), f2bf(a0.z), f2bf(a0.w),
                          f2bf(a1.x), f2bf(a1.y), f2bf(a1.z), f2bf(a1.w)};
            const int kc = (kh + kk) >> 3;
            *(short8*)&lrow[(kc ^ (c & 7)) * 8] = *(const short8*)tmp;
        }
    }
    stage_xt(&xt[0][0], xb, 0, wave, lane);
    __syncthreads();

    f32x4 acc[4][4];
#pragma unroll
    for (int mf = 0; mf < 4; ++mf)
#pragma unroll
        for (int nf = 0; nf < 4; ++nf) acc[mf][nf] = (f32x4){0.f, 0.f, 0.f, 0.f};

    int buf = 0;
    for (int ks = 0; ks < 8; ++ks) {
        if (ks < 7) stage_xt(&xt[buf ^ 1][0], xb, ks + 1, wave, lane);

        short8 af[4], bf[4];
#pragma unroll
        for (int mf = 0; mf < 4; ++mf) {
            const int c = wr * 64 + mf * 16 + li;
            af[mf] = *(const short8*)&wl[c * 256 + (((ks * 4 + g) ^ (li & 7)) * 8)];
        }
#pragma unroll
        for (int nf = 0; nf < 4; ++nf) {
            const int j = wc * 64 + nf * 16 + li;
            bf[nf] = *(const short8*)&xt[buf][j * 32 + ((g ^ ((j >> 1) & 3)) * 8)];
        }
        __builtin_amdgcn_s_setprio(1);
#pragma unroll
        for (int mf = 0; mf < 4; ++mf)
#pragma unroll
            for (int nf = 0; nf < 4; ++nf)
                acc[mf][nf] = __builtin_amdgcn_mfma_f32_16x16x32_bf16(
                    af[mf], bf[nf], acc[mf][nf], 0, 0, 0);
        __builtin_amdgcn_s_setprio(0);
        __syncthreads();
        buf ^= 1;
    }

    // ---- epilogue: write packed fp8 V
#pragma unroll
    for (int mf = 0; mf < 4; ++mf) {
#pragma unroll
        for (int r = 0; r < 4; ++r) {
            const int c = ct * 128 + wr * 64 + mf * 16 + 4 * g + r;
            const float bv = bias[c];
#pragma unroll
            for (int nf = 0; nf < 4; ++nf) {
                const int j = jt * 128 + wc * 64 + nf * 16 + li;
                dstB[(size_t)(j >> 5) * 8192 + ((j >> 3) & 3) * 2048
                     + c * 8 + (j & 7)] = f2fp8(acc[mf][nf][r] + bv);
            }
        }
    }
}

// ---------------------------------------------------------------------------
// Kernel 3: flash attention, static-max exp2 softmax, c-split, fp8 PV.
// block 256 = 4 waves = 2 j-halves (grp) x 2 i-halves (wg); R=2 (32 i/wave);
// each block owns a 128-c half (ct).  acc[2][8] = 64 VGPRs, no spill.
// V: fp8 packed [jblk][p][c][8B]; stage = 2 linear 1KB copies per wave;
// PV = mfma_f32_16x16x32_fp8_fp8, B operand one b64/lane (4 dwords/bank min).
// P -> fp8 via v_cvt_pk_fp8_f32 (4 insts/tile, replaces ~40 VALU bf16 pack).
// grid 1024: n = slice + 8*(ib + 64*ct); slice = n%8 -> XCD affinity.
// [Session converged config: best measured 94.9us attn / 139.3us total.]
// ---------------------------------------------------------------------------
__global__ __launch_bounds__(256, 4) void attn_fwd(
    const u16* __restrict__ Q, const u16* __restrict__ K,
    const u8* __restrict__ V, u16* __restrict__ O)
{
    __shared__ __align__(16) u8 vlds[2][2][4096];   // [grp][buf] 16 KB total
    __shared__ float lscr[2][2][64][2];             // [grp][wg][lane][it]

    const int n  = blockIdx.x;
    const int s  = n & 7;              // slice -> XCD (n%8)
    const int ib = (n >> 3) & 63;      // i-block of 64 rows
    const int ct = n >> 9;             // c-half
    const u16* q = Q + (size_t)s * N_TOK * D_DIM;
    const u16* k = K + (size_t)s * N_TOK * D_DIM;
    const u8*  v = V + (size_t)s * N_TOK * C_DIM + ct * 1024;  // c-half in p-chunks
    u16*       o = O + (size_t)s * N_TOK * C_DIM + ct * 128;

    const int tid  = threadIdx.x;
    const int wave = tid >> 6;
    const int lane = tid & 63;
    const int grp  = wave >> 1;        // j-half
    const int wg   = wave & 1;
    const int g    = lane >> 4;
    const int li   = lane & 15;
    const int i0   = ib * 64 + wg * 32;
    const int jbase = grp * (N_TOK / 2);
    const int NP = N_TOK / 2 / 32;     // 64 periods of 32 j

    short8 qf[2];
    qf[0] = *(const short8*)(q + (size_t)(i0 + li) * D_DIM + 8 * g);
    qf[1] = *(const short8*)(q + (size_t)(i0 + 16 + li) * D_DIM + 8 * g);

    f32x4 acc[2][8];
#pragma unroll
    for (int it = 0; it < 2; ++it)
#pragma unroll
        for (int cf = 0; cf < 8; ++cf) acc[it][cf] = (f32x4){0.f, 0.f, 0.f, 0.f};
    float lsum[2] = {0.f, 0.f};

    // prologue: V tile 0 (2 x 1KB linear chunks per wave)
    {
        const u8* tile = v + (size_t)(jbase >> 5) * 8192;
#pragma unroll
        for (int ii = 0; ii < 2; ++ii) {
            const int p = wg * 2 + ii;
            __builtin_amdgcn_global_load_lds(
                (const __attribute__((address_space(1))) void*)(tile + p * 2048 + lane * 16),
                (__attribute__((address_space(3))) void*)(&vlds[grp][0][0] + p * 1024),
                16, 0, 0);
        }
    }
    __syncthreads();

    int buf = 0;
    for (int p = 0; p < NP; ++p) {
        if (p < NP - 1) {               // stage next V tile (async)
            const u8* tile = v + (size_t)((jbase + (p + 1) * 32) >> 5) * 8192;
            u8* dst = &vlds[grp][buf ^ 1][0];
#pragma unroll
            for (int ii = 0; ii < 2; ++ii) {
                const int pc = wg * 2 + ii;
                __builtin_amdgcn_global_load_lds(
                    (const __attribute__((address_space(1))) void*)(tile + pc * 2048 + lane * 16),
                    (__attribute__((address_space(3))) void*)(dst + pc * 1024),
                    16, 0, 0);
            }
        }

        // K fragments for this period (L2-resident; TLP hides latency)
        const int j0 = jbase + p * 32;
        const short8 ke = *(const short8*)(k + (size_t)(j0 + 2 * li    ) * D_DIM + 8 * g);
        const short8 ko = *(const short8*)(k + (size_t)(j0 + 2 * li + 1) * D_DIM + 8 * g);

        const f32x4 z = (f32x4){0.f, 0.f, 0.f, 0.f};
        i64 paL[2];
#pragma unroll
        for (int it = 0; it < 2; ++it) {
            f32x4 se = __builtin_amdgcn_mfma_f32_16x16x32_bf16(ke, qf[it], z, 0, 0, 0);
            f32x4 so = __builtin_amdgcn_mfma_f32_16x16x32_bf16(ko, qf[it], z, 0, 0, 0);
            float pe[4], po[4];
#pragma unroll
            for (int r = 0; r < 4; ++r) {
                pe[r] = exp2_fast(se[r]);   // P = 2^(s*log2e), static shift
                po[r] = exp2_fast(so[r]);
            }
            lsum[it] += ((pe[0] + po[0]) + (pe[1] + po[1]))
                      + ((pe[2] + po[2]) + (pe[3] + po[3]));
            // pack P -> 8 fp8 bytes: byte e = j (8g+e); e=2r even (pe), 2r+1 odd (po)
            int w0 = pk_fp8<false>(pe[0], po[0], 0);
            w0     = pk_fp8<true >(pe[1], po[1], w0);
            int w1 = pk_fp8<false>(pe[2], po[2], 0);
            w1     = pk_fp8<true >(pe[3], po[3], w1);
            paL[it] = (i64)(((unsigned long long)(unsigned)w1 << 32) | (unsigned)w0);
        }

        // O += P * V^T ; fp8 MFMA, one b64 V read feeds both i-tiles
        const u8* vb = &vlds[grp][buf][0];
        const i64* vbL = (const i64*)(vb + g * 1024 + li * 8);
        __builtin_amdgcn_s_setprio(1);
#pragma unroll
        for (int cf = 0; cf < 8; ++cf) {
            const i64 vfL = vbL[cf * 16];
            acc[0][cf] = __builtin_amdgcn_mfma_f32_16x16x32_fp8_fp8(paL[0], vfL, acc[0][cf], 0, 0, 0);
            acc[1][cf] = __builtin_amdgcn_mfma_f32_16x16x32_fp8_fp8(paL[1], vfL, acc[1][cf], 0, 0, 0);
        }
        __builtin_amdgcn_s_setprio(0);
        __syncthreads();
        buf ^= 1;
    }

    // ---- merge the 2 j-half partials: pure add (static-max => same scale) ----
#pragma unroll
    for (int it = 0; it < 2; ++it) {
        lsum[it] += __shfl_xor(lsum[it], 16);
        lsum[it] += __shfl_xor(lsum[it], 32);
        lscr[grp][wg][lane][it] = lsum[it];
    }

    f32x4* pv = (f32x4*)&vlds[0][0][0];   // reuse 16 KB as merge scratch
#pragma unroll
    for (int it = 0; it < 2; ++it) {
        __syncthreads();
        if (grp == 1) {
#pragma unroll
            for (int cf = 0; cf < 8; ++cf)
                pv[(wg * 8 + cf) * 64 + lane] = acc[it][cf];
        }
        __syncthreads();
        if (grp == 0) {
#pragma unroll
            for (int cf = 0; cf < 8; ++cf) {
                const f32x4 o4 = pv[(wg * 8 + cf) * 64 + lane];
                acc[it][cf][0] += o4[0]; acc[it][cf][1] += o4[1];
                acc[it][cf][2] += o4[2]; acc[it][cf][3] += o4[3];
            }
        }
    }

    if (grp == 0) {
#pragma unroll
        for (int it = 0; it < 2; ++it) {
            const float linv = 1.0f / (lscr[0][wg][lane][it] + lscr[1][wg][lane][it]);
            float lr[4];
#pragma unroll
            for (int r = 0; r < 4; ++r) lr[r] = __shfl(linv, 4 * g + r);
#pragma unroll
            for (int cf = 0; cf < 8; ++cf)
#pragma unroll
                for (int r = 0; r < 4; ++r)
                    o[(size_t)(i0 + it * 16 + 4 * g + r) * C_DIM + cf * 16 + li] =
                        f2bf(acc[it][cf][r] * lr[r]);
        }
    }
}

// ---------------------------------------------------------------------------
// Kernel 4: out[b][c][i] = x1 + x2 + O1[b][i][c] + O2[b][i][c]  (LDS transpose)
// ---------------------------------------------------------------------------
__global__ __launch_bounds__(256) void epilogue(
    const float* __restrict__ x1, const float* __restrict__ x2,
    const u16* __restrict__ O, float* __restrict__ out)
{
    __shared__ float tl[64][65];
    const int it = blockIdx.x, ct = blockIdx.y, b = blockIdx.z;
    const int tid = threadIdx.x;
    const int cl = tid & 63, r0 = tid >> 6;

    const u16* O1 = O + (size_t)(b)     * N_TOK * C_DIM;
    const u16* O2 = O + (size_t)(4 + b) * N_TOK * C_DIM;

#pragma unroll
    for (int rr = 0; rr < 16; ++rr) {
        const int il = r0 + rr * 4;
        const size_t off = (size_t)(it * 64 + il) * C_DIM + ct * 64 + cl;
        tl[il][cl] = bf2f(O1[off]) + bf2f(O2[off]);
    }
    __syncthreads();
#pragma unroll
    for (int rr = 0; rr < 16; ++rr) {
        const int c2 = r0 + rr * 4;
        const size_t idx = ((size_t)b * C_DIM + ct * 64 + c2) * N_TOK + it * 64 + cl;
        out[idx] = x1[idx] + x2[idx] + tl[cl][c2];
    }
}

// ---------------------------------------------------------------------------
extern "C" void kernel_launch(void* const* d_in, const int* in_sizes, int n_in,
                              void* d_out, int out_size, void* d_ws, size_t ws_size,
                              hipStream_t stream)
{
    const float* x1  = (const float*)d_in[0];
    const float* x2  = (const float*)d_in[1];
    const float* wq1 = (const float*)d_in[2];
    const float* bq1 = (const float*)d_in[3];
    const float* wk1 = (const float*)d_in[4];
    const float* bk1 = (const float*)d_in[5];
    const float* wv1 = (const float*)d_in[6];
    const float* bv1 = (const float*)d_in[7];
    const float* wq2 = (const float*)d_in[8];
    const float* bq2 = (const float*)d_in[9];
    const float* wk2 = (const float*)d_in[10];
    const float* bk2 = (const float*)d_in[11];
    const float* wv2 = (const float*)d_in[12];
    const float* bv2 = (const float*)d_in[13];
    float* out = (float*)d_out;

    // ws layout: Q bf16 2MB | K bf16 2MB | V fp8 packed 8MB | O bf16 16MB
    u16* wsQ = (u16*)d_ws;
    u16* wsK = wsQ + (size_t)8 * N_TOK * D_DIM;
    u8*  wsV = (u8*)(wsK + (size_t)8 * N_TOK * D_DIM);
    u16* wsO = (u16*)(wsV + (size_t)8 * N_TOK * C_DIM);

    qk_proj<<<dim3(64, 16), 256, 0, stream>>>(x1, x2, wq1, bq1, wk1, bk1,
                                              wq2, bq2, wk2, bk2, wsQ, wsK);
    v_proj<<<dim3(32, 2, 8), 256, 0, stream>>>(x2, wv1, bv1, wv2, bv2, wsV);
    attn_fwd<<<dim3(1024), 256, 0, stream>>>(wsQ, wsK, wsV, wsO);
    epilogue<<<dim3(64, 4, 4), 256, 0, stream>>>(x1, x2, wsO, out);
}